// Round 1
// baseline (31.353 us; speedup 1.0000x reference)
//
#include <hip/hip_runtime.h>
#include <math.h>

#define NPTS 512
#define DIM  2048
#define MARGIN_F 0.5f
#define KZ 8
#define KCHUNK (DIM / KZ)   // 256

typedef __attribute__((ext_vector_type(4))) float f32x4;
typedef __attribute__((ext_vector_type(8))) short bf16x8;
typedef __attribute__((ext_vector_type(4))) unsigned int u32x4;

// f32 pair -> packed bf16 (RNE). Lowers to v_cvt_pk_bf16_f32 on gfx950.
// The previous hand-rolled integer RNE was ~4-5 VALU ops/elem; this is ~0.5.
// Rounding is bit-identical (both RNE).
__device__ inline unsigned int pkbf(float lo, float hi) {
    unsigned short ul = __builtin_bit_cast(unsigned short, (__bf16)lo);
    unsigned short uh = __builtin_bit_cast(unsigned short, (__bf16)hi);
    return (unsigned int)ul | ((unsigned int)uh << 16);
}

// ---------- kernel 1: split-K Gram partials, f32->bf16 fused into staging.
// grid (8, 8, 8) = 512 blocks (2/CU); 256 thr = 4 waves as 2x2, each wave a
// 32x32 quadrant = 2x2 frags of 16x16x32. Diagonal tiles also emit a compact
// per-plane diag[z][512]. Also zero-inits the ticket counter for kernel 2's
// fused finalize (kernel boundary guarantees visibility; workspace may be
// poisoned by the harness so we cannot rely on its contents).
__global__ __launch_bounds__(256) void gram_kernel(const float* __restrict__ x,
                                                   float* __restrict__ part,
                                                   float* __restrict__ diag,
                                                   unsigned int* __restrict__ ctr) {
    __shared__ __align__(16) unsigned short As[64][72];  // +8 pad
    __shared__ __align__(16) unsigned short Bs[64][72];

    int bx = blockIdx.x, by = blockIdx.y, z = blockIdx.z;
    int tid = threadIdx.x;

    if (bx == 0 && by == 0 && z == 0 && tid == 0) ctr[0] = 0u;

    int lr = tid >> 2;            // staging row 0..63
    int lc = (tid & 3) * 16;      // staging col (elements) 0,16,32,48

    const float* arow = x + (size_t)(bx * 64 + lr) * DIM + (size_t)z * KCHUNK + lc;
    const float* brow = x + (size_t)(by * 64 + lr) * DIM + (size_t)z * KCHUNK + lc;

    int w = tid >> 6, lane = tid & 63;
    int wr = (w >> 1) * 32, wc = (w & 1) * 32;
    int fr = lane & 15, ko = (lane >> 4) * 8;

    f32x4 acc[2][2] = {};

    for (int ks = 0; ks < KCHUNK; ks += 64) {
        float4 a0 = *reinterpret_cast<const float4*>(arow + ks);
        float4 a1 = *reinterpret_cast<const float4*>(arow + ks + 4);
        float4 a2 = *reinterpret_cast<const float4*>(arow + ks + 8);
        float4 a3 = *reinterpret_cast<const float4*>(arow + ks + 12);
        float4 b0 = *reinterpret_cast<const float4*>(brow + ks);
        float4 b1 = *reinterpret_cast<const float4*>(brow + ks + 4);
        float4 b2 = *reinterpret_cast<const float4*>(brow + ks + 8);
        float4 b3 = *reinterpret_cast<const float4*>(brow + ks + 12);
        u32x4 wa0 = { pkbf(a0.x, a0.y), pkbf(a0.z, a0.w), pkbf(a1.x, a1.y), pkbf(a1.z, a1.w) };
        u32x4 wa1 = { pkbf(a2.x, a2.y), pkbf(a2.z, a2.w), pkbf(a3.x, a3.y), pkbf(a3.z, a3.w) };
        u32x4 wb0 = { pkbf(b0.x, b0.y), pkbf(b0.z, b0.w), pkbf(b1.x, b1.y), pkbf(b1.z, b1.w) };
        u32x4 wb1 = { pkbf(b2.x, b2.y), pkbf(b2.z, b2.w), pkbf(b3.x, b3.y), pkbf(b3.z, b3.w) };
        // byte offsets: lr*144 + lc*2 with lc in {0,16,32,48} -> all 16B-aligned
        *reinterpret_cast<u32x4*>(&As[lr][lc])     = wa0;
        *reinterpret_cast<u32x4*>(&As[lr][lc + 8]) = wa1;
        *reinterpret_cast<u32x4*>(&Bs[lr][lc])     = wb0;
        *reinterpret_cast<u32x4*>(&Bs[lr][lc + 8]) = wb1;
        __syncthreads();
#pragma unroll
        for (int kc = 0; kc < 2; ++kc) {
            bf16x8 fa0 = *reinterpret_cast<const bf16x8*>(&As[wr + fr][kc * 32 + ko]);
            bf16x8 fa1 = *reinterpret_cast<const bf16x8*>(&As[wr + 16 + fr][kc * 32 + ko]);
            bf16x8 fb0 = *reinterpret_cast<const bf16x8*>(&Bs[wc + fr][kc * 32 + ko]);
            bf16x8 fb1 = *reinterpret_cast<const bf16x8*>(&Bs[wc + 16 + fr][kc * 32 + ko]);
            acc[0][0] = __builtin_amdgcn_mfma_f32_16x16x32_bf16(fa0, fb0, acc[0][0], 0, 0, 0);
            acc[0][1] = __builtin_amdgcn_mfma_f32_16x16x32_bf16(fa0, fb1, acc[0][1], 0, 0, 0);
            acc[1][0] = __builtin_amdgcn_mfma_f32_16x16x32_bf16(fa1, fb0, acc[1][0], 0, 0, 0);
            acc[1][1] = __builtin_amdgcn_mfma_f32_16x16x32_bf16(fa1, fb1, acc[1][1], 0, 0, 0);
        }
        __syncthreads();
    }

    float* pg = part + (size_t)z * NPTS * NPTS;
    int rbase = bx * 64 + wr + ((lane >> 4) << 2);  // C/D: row = (lane>>4)*4 + reg
    int cbase = by * 64 + wc + fr;                  //      col = lane&15
#pragma unroll
    for (int m = 0; m < 2; ++m)
#pragma unroll
        for (int n = 0; n < 2; ++n) {
            f32x4 v = acc[m][n];
#pragma unroll
            for (int j = 0; j < 4; ++j)
                pg[(size_t)(rbase + m * 16 + j) * NPTS + (cbase + n * 16)] = v[j];
        }

    // compact diagonal: tile diag lives in waves with wr==wc, frags m==n,
    // lanes where fr>>2 == lane>>4 (then row==col at j = fr&3).
    if (bx == by && wr == wc && (fr >> 2) == (lane >> 4)) {
        int j = fr & 3;
#pragma unroll
        for (int m = 0; m < 2; ++m)
            diag[(size_t)z * NPTS + bx * 64 + wr + m * 16 + fr] = acc[m][m][j];
    }
}

// ---------- kernel 2: per-anchor hinge + fused last-block finalize ----------
__global__ __launch_bounds__(256) void triplet_kernel(const float* __restrict__ part,
                                                      const float* __restrict__ diag,
                                                      const int* __restrict__ traw,
                                                      float* __restrict__ psum,
                                                      unsigned int* __restrict__ pcnt,
                                                      unsigned int* __restrict__ ctr,
                                                      float* __restrict__ out) {
    __shared__ float drow[NPTS];
    __shared__ float sqv[NPTS];
    __shared__ int   tl[NPTS];
    __shared__ int   pos[NPTS];
    __shared__ int   is64;
    __shared__ unsigned long long wmask[8];
    __shared__ float wsum[4];
    __shared__ unsigned int wcnt[4];
    __shared__ unsigned int ticket_s;

    int a = blockIdx.x, tid = threadIdx.x;
    int lane = tid & 63, wid = tid >> 6;
    if (tid == 0) is64 = 1;
    __syncthreads();

    // int64 vs int32 targets sniff (ids < 64 -> odd words all zero iff i64)
    for (int i = tid; i < NPTS / 2; i += 256)
        if (traw[2 * i + 1] != 0) is64 = 0;
    __syncthreads();
    if (is64) { for (int i = tid; i < NPTS; i += 256) tl[i] = traw[2 * i]; }
    else      { for (int i = tid; i < NPTS; i += 256) tl[i] = traw[i]; }

    // squared norms from compact per-plane diag (contiguous reads)
    for (int j = tid; j < NPTS; j += 256) {
        float s = 0.f;
#pragma unroll
        for (int z = 0; z < KZ; ++z) s += diag[(size_t)z * NPTS + j];
        sqv[j] = s;
    }
    __syncthreads();

    // dist row a: sum KZ partial planes. float2 over NPTS/2 = exactly one
    // iteration for all 256 threads (the old float4/NPTS/4 loop idled half
    // the block).
    const size_t PL = (size_t)NPTS * NPTS;
    float sqa = sqv[a];
    {
        int i = tid;  // i < NPTS/2 == 256 always
        float2 g2 = {0.f, 0.f};
#pragma unroll
        for (int z = 0; z < KZ; ++z) {
            float2 gz = reinterpret_cast<const float2*>(part + (size_t)z * PL + (size_t)a * NPTS)[i];
            g2.x += gz.x; g2.y += gz.y;
        }
        float d2;
        d2 = sqa + sqv[2 * i + 0] - 2.f * g2.x; drow[2 * i + 0] = d2 > 0.f ? sqrtf(d2) : 0.f;
        d2 = sqa + sqv[2 * i + 1] - 2.f * g2.y; drow[2 * i + 1] = d2 > 0.f ? sqrtf(d2) : 0.f;
    }
    __syncthreads();

    // deterministic positive-list compaction via ballot prefix
    int ta = tl[a];
    unsigned long long bal[2];
    bool m[2];
#pragma unroll
    for (int p = 0; p < 2; ++p) {
        int j = p * 256 + tid;
        m[p] = (tl[j] == ta) && (j != a);
        bal[p] = __ballot(m[p]);
        if (lane == 0) wmask[p * 4 + wid] = bal[p];
    }
    __syncthreads();
    int np = 0;
#pragma unroll
    for (int k = 0; k < 8; ++k) np += __popcll(wmask[k]);
#pragma unroll
    for (int p = 0; p < 2; ++p) {
        if (m[p]) {
            int widx = p * 4 + wid, base = 0;
            for (int k = 0; k < widx; ++k) base += __popcll(wmask[k]);
            base += __popcll(bal[p] & ((1ull << lane) - 1ull));
            pos[base] = p * 256 + tid;
        }
    }
    __syncthreads();

    float sum = 0.f;
    unsigned int cnt = 0;
    int tot = np << 9;
    for (int idx = tid; idx < tot; idx += 256) {
        int p = pos[idx >> 9];
        int n = idx & (NPTS - 1);
        if (tl[n] != ta) {
            float v = drow[p] - drow[n] + MARGIN_F;
            if (v > 0.f) { sum += v; cnt++; }
        }
    }

    for (int off = 32; off; off >>= 1) {
        sum += __shfl_down(sum, off);
        cnt += __shfl_down(cnt, off);
    }
    if (lane == 0) { wsum[wid] = sum; wcnt[wid] = cnt; }
    __syncthreads();

    // publish per-anchor partials, then atomic ticket; last block finalizes.
    if (tid == 0) {
        psum[a] = wsum[0] + wsum[1] + wsum[2] + wsum[3];
        pcnt[a] = wcnt[0] + wcnt[1] + wcnt[2] + wcnt[3];
        __threadfence();                       // release psum/pcnt (device scope)
        ticket_s = atomicAdd(ctr, 1u);
    }
    __syncthreads();
    if (ticket_s == NPTS - 1) {
        __threadfence();                       // acquire other blocks' psum/pcnt
        float s = psum[tid] + psum[tid + 256];
        unsigned int c = pcnt[tid] + pcnt[tid + 256];
        for (int off = 32; off; off >>= 1) {
            s += __shfl_down(s, off);
            c += __shfl_down(c, off);
        }
        if (lane == 0) { wsum[wid] = s; wcnt[wid] = c; }
        __syncthreads();
        if (tid == 0) {
            float totv = wsum[0] + wsum[1] + wsum[2] + wsum[3];
            unsigned int cc = wcnt[0] + wcnt[1] + wcnt[2] + wcnt[3];
            out[0] = totv / (float)(cc ? cc : 1u);
        }
    }
}

extern "C" void kernel_launch(void* const* d_in, const int* in_sizes, int n_in,
                              void* d_out, int out_size, void* d_ws, size_t ws_size,
                              hipStream_t stream) {
    const float* x = (const float*)d_in[0];
    const int* t = (const int*)d_in[1];
    float* out = (float*)d_out;

    char* ws = (char*)d_ws;
    const size_t OFF_PART = 0;                                  // 8 MiB (8 planes)
    const size_t OFF_DIAG = (size_t)KZ * NPTS * NPTS * 4;       // 16 KiB
    const size_t OFF_PSUM = OFF_DIAG + (size_t)KZ * NPTS * 4;   // 2 KiB
    const size_t OFF_PCNT = OFF_PSUM + 2048;                    // 2 KiB
    const size_t OFF_CTR  = OFF_PCNT + 2048;                    // 4 B

    float* part        = (float*)(ws + OFF_PART);
    float* diag        = (float*)(ws + OFF_DIAG);
    float* psum        = (float*)(ws + OFF_PSUM);
    unsigned int* pcnt = (unsigned int*)(ws + OFF_PCNT);
    unsigned int* ctr  = (unsigned int*)(ws + OFF_CTR);

    gram_kernel<<<dim3(8, 8, KZ), 256, 0, stream>>>(x, part, diag, ctr);
    triplet_kernel<<<NPTS, 256, 0, stream>>>(part, diag, t, psum, pcnt, ctr, out);
}

// Round 2
// 25.482 us; speedup vs baseline: 1.2304x; 1.2304x over previous
//
#include <hip/hip_runtime.h>
#include <math.h>

#define NPTS 512
#define DIM  2048
#define MARGIN_F 0.5f
#define KZ 8
#define KCHUNK (DIM / KZ)   // 256

typedef __attribute__((ext_vector_type(4))) float f32x4;
typedef __attribute__((ext_vector_type(8))) short bf16x8;
typedef __attribute__((ext_vector_type(4))) unsigned int u32x4;

// f32 pair -> packed bf16 (RNE). Lowers to v_cvt_pk_bf16_f32 on gfx950
// (guide m240: scalar cast is the fast path). Replaces the hand-rolled
// integer RNE (~4-5 VALU/elem) with ~0.5 VALU/elem. Rounding identical (RNE).
__device__ inline unsigned int pkbf(float lo, float hi) {
    unsigned short ul = __builtin_bit_cast(unsigned short, (__bf16)lo);
    unsigned short uh = __builtin_bit_cast(unsigned short, (__bf16)hi);
    return (unsigned int)ul | ((unsigned int)uh << 16);
}

// ---------- kernel 1: split-K Gram partials, f32->bf16 fused into staging.
// grid (8, 8, 8) = 512 blocks (2/CU); 256 thr = 4 waves as 2x2, each wave a
// 32x32 quadrant = 2x2 frags of 16x16x32. Diagonal tiles also emit a compact
// per-plane diag[z][512] so triplet avoids a scattered gather.
__global__ __launch_bounds__(256) void gram_kernel(const float* __restrict__ x,
                                                   float* __restrict__ part,
                                                   float* __restrict__ diag) {
    __shared__ __align__(16) unsigned short As[64][72];  // +8 pad
    __shared__ __align__(16) unsigned short Bs[64][72];

    int bx = blockIdx.x, by = blockIdx.y, z = blockIdx.z;
    int tid = threadIdx.x;
    int lr = tid >> 2;            // staging row 0..63
    int lc = (tid & 3) * 16;      // staging col (elements) 0,16,32,48

    const float* arow = x + (size_t)(bx * 64 + lr) * DIM + (size_t)z * KCHUNK + lc;
    const float* brow = x + (size_t)(by * 64 + lr) * DIM + (size_t)z * KCHUNK + lc;

    int w = tid >> 6, lane = tid & 63;
    int wr = (w >> 1) * 32, wc = (w & 1) * 32;
    int fr = lane & 15, ko = (lane >> 4) * 8;

    f32x4 acc[2][2] = {};

    for (int ks = 0; ks < KCHUNK; ks += 64) {
        float4 a0 = *reinterpret_cast<const float4*>(arow + ks);
        float4 a1 = *reinterpret_cast<const float4*>(arow + ks + 4);
        float4 a2 = *reinterpret_cast<const float4*>(arow + ks + 8);
        float4 a3 = *reinterpret_cast<const float4*>(arow + ks + 12);
        float4 b0 = *reinterpret_cast<const float4*>(brow + ks);
        float4 b1 = *reinterpret_cast<const float4*>(brow + ks + 4);
        float4 b2 = *reinterpret_cast<const float4*>(brow + ks + 8);
        float4 b3 = *reinterpret_cast<const float4*>(brow + ks + 12);
        u32x4 wa0 = { pkbf(a0.x, a0.y), pkbf(a0.z, a0.w), pkbf(a1.x, a1.y), pkbf(a1.z, a1.w) };
        u32x4 wa1 = { pkbf(a2.x, a2.y), pkbf(a2.z, a2.w), pkbf(a3.x, a3.y), pkbf(a3.z, a3.w) };
        u32x4 wb0 = { pkbf(b0.x, b0.y), pkbf(b0.z, b0.w), pkbf(b1.x, b1.y), pkbf(b1.z, b1.w) };
        u32x4 wb1 = { pkbf(b2.x, b2.y), pkbf(b2.z, b2.w), pkbf(b3.x, b3.y), pkbf(b3.z, b3.w) };
        // byte offsets: lr*144 + lc*2 with lc in {0,16,32,48} -> all 16B-aligned
        *reinterpret_cast<u32x4*>(&As[lr][lc])     = wa0;
        *reinterpret_cast<u32x4*>(&As[lr][lc + 8]) = wa1;
        *reinterpret_cast<u32x4*>(&Bs[lr][lc])     = wb0;
        *reinterpret_cast<u32x4*>(&Bs[lr][lc + 8]) = wb1;
        __syncthreads();
#pragma unroll
        for (int kc = 0; kc < 2; ++kc) {
            bf16x8 fa0 = *reinterpret_cast<const bf16x8*>(&As[wr + fr][kc * 32 + ko]);
            bf16x8 fa1 = *reinterpret_cast<const bf16x8*>(&As[wr + 16 + fr][kc * 32 + ko]);
            bf16x8 fb0 = *reinterpret_cast<const bf16x8*>(&Bs[wc + fr][kc * 32 + ko]);
            bf16x8 fb1 = *reinterpret_cast<const bf16x8*>(&Bs[wc + 16 + fr][kc * 32 + ko]);
            acc[0][0] = __builtin_amdgcn_mfma_f32_16x16x32_bf16(fa0, fb0, acc[0][0], 0, 0, 0);
            acc[0][1] = __builtin_amdgcn_mfma_f32_16x16x32_bf16(fa0, fb1, acc[0][1], 0, 0, 0);
            acc[1][0] = __builtin_amdgcn_mfma_f32_16x16x32_bf16(fa1, fb0, acc[1][0], 0, 0, 0);
            acc[1][1] = __builtin_amdgcn_mfma_f32_16x16x32_bf16(fa1, fb1, acc[1][1], 0, 0, 0);
        }
        __syncthreads();
    }

    float* pg = part + (size_t)z * NPTS * NPTS;
    int rbase = bx * 64 + wr + ((lane >> 4) << 2);  // C/D: row = (lane>>4)*4 + reg
    int cbase = by * 64 + wc + fr;                  //      col = lane&15
#pragma unroll
    for (int m = 0; m < 2; ++m)
#pragma unroll
        for (int n = 0; n < 2; ++n) {
            f32x4 v = acc[m][n];
#pragma unroll
            for (int j = 0; j < 4; ++j)
                pg[(size_t)(rbase + m * 16 + j) * NPTS + (cbase + n * 16)] = v[j];
        }

    // compact diagonal: tile diag lives in waves with wr==wc, frags m==n,
    // lanes where fr>>2 == lane>>4 (then row==col at j = fr&3).
    if (bx == by && wr == wc && (fr >> 2) == (lane >> 4)) {
        int j = fr & 3;
#pragma unroll
        for (int m = 0; m < 2; ++m)
            diag[(size_t)z * NPTS + bx * 64 + wr + m * 16 + fr] = acc[m][m][j];
    }
}

// ---------- kernel 2: per-anchor hinge; norms from compact diag ----------
__global__ __launch_bounds__(256) void triplet_kernel(const float* __restrict__ part,
                                                      const float* __restrict__ diag,
                                                      const int* __restrict__ traw,
                                                      float* __restrict__ psum,
                                                      unsigned int* __restrict__ pcnt) {
    __shared__ float drow[NPTS];
    __shared__ float sqv[NPTS];
    __shared__ int   tl[NPTS];
    __shared__ int   pos[NPTS];
    __shared__ int   is64;
    __shared__ unsigned long long wmask[8];
    __shared__ float wsum[4];
    __shared__ unsigned int wcnt[4];

    int a = blockIdx.x, tid = threadIdx.x;
    int lane = tid & 63, wid = tid >> 6;
    if (tid == 0) is64 = 1;
    __syncthreads();

    // int64 vs int32 targets sniff (ids < 64 -> odd words all zero iff i64)
    for (int i = tid; i < NPTS / 2; i += 256)
        if (traw[2 * i + 1] != 0) is64 = 0;
    __syncthreads();
    if (is64) { for (int i = tid; i < NPTS; i += 256) tl[i] = traw[2 * i]; }
    else      { for (int i = tid; i < NPTS; i += 256) tl[i] = traw[i]; }

    // squared norms from compact per-plane diag (contiguous reads)
    for (int j = tid; j < NPTS; j += 256) {
        float s = 0.f;
#pragma unroll
        for (int z = 0; z < KZ; ++z) s += diag[(size_t)z * NPTS + j];
        sqv[j] = s;
    }
    __syncthreads();

    // dist row a: sum KZ partial planes (vectorized) + sqrt epilogue
    const size_t PL = (size_t)NPTS * NPTS;
    float sqa = sqv[a];
    for (int i = tid; i < NPTS / 4; i += 256) {
        float4 g4 = {0.f, 0.f, 0.f, 0.f};
#pragma unroll
        for (int z = 0; z < KZ; ++z) {
            float4 gz = reinterpret_cast<const float4*>(part + (size_t)z * PL + (size_t)a * NPTS)[i];
            g4.x += gz.x; g4.y += gz.y; g4.z += gz.z; g4.w += gz.w;
        }
        float d2;
        d2 = sqa + sqv[4 * i + 0] - 2.f * g4.x; drow[4 * i + 0] = d2 > 0.f ? sqrtf(d2) : 0.f;
        d2 = sqa + sqv[4 * i + 1] - 2.f * g4.y; drow[4 * i + 1] = d2 > 0.f ? sqrtf(d2) : 0.f;
        d2 = sqa + sqv[4 * i + 2] - 2.f * g4.z; drow[4 * i + 2] = d2 > 0.f ? sqrtf(d2) : 0.f;
        d2 = sqa + sqv[4 * i + 3] - 2.f * g4.w; drow[4 * i + 3] = d2 > 0.f ? sqrtf(d2) : 0.f;
    }
    __syncthreads();

    // deterministic positive-list compaction via ballot prefix
    int ta = tl[a];
    unsigned long long bal[2];
    bool m[2];
#pragma unroll
    for (int p = 0; p < 2; ++p) {
        int j = p * 256 + tid;
        m[p] = (tl[j] == ta) && (j != a);
        bal[p] = __ballot(m[p]);
        if (lane == 0) wmask[p * 4 + wid] = bal[p];
    }
    __syncthreads();
    int np = 0;
#pragma unroll
    for (int k = 0; k < 8; ++k) np += __popcll(wmask[k]);
#pragma unroll
    for (int p = 0; p < 2; ++p) {
        if (m[p]) {
            int widx = p * 4 + wid, base = 0;
            for (int k = 0; k < widx; ++k) base += __popcll(wmask[k]);
            base += __popcll(bal[p] & ((1ull << lane) - 1ull));
            pos[base] = p * 256 + tid;
        }
    }
    __syncthreads();

    float sum = 0.f;
    unsigned int cnt = 0;
    int tot = np << 9;
    for (int idx = tid; idx < tot; idx += 256) {
        int p = pos[idx >> 9];
        int n = idx & (NPTS - 1);
        if (tl[n] != ta) {
            float v = drow[p] - drow[n] + MARGIN_F;
            if (v > 0.f) { sum += v; cnt++; }
        }
    }

    for (int off = 32; off; off >>= 1) {
        sum += __shfl_down(sum, off);
        cnt += __shfl_down(cnt, off);
    }
    if (lane == 0) { wsum[wid] = sum; wcnt[wid] = cnt; }
    __syncthreads();
    if (tid == 0) {
        psum[a] = wsum[0] + wsum[1] + wsum[2] + wsum[3];
        pcnt[a] = wcnt[0] + wcnt[1] + wcnt[2] + wcnt[3];
    }
}

// ---------- kernel 3: final reduction over 512 per-anchor partials ----------
__global__ __launch_bounds__(256) void finalize_kernel(const float* __restrict__ psum,
                                                       const unsigned int* __restrict__ pcnt,
                                                       float* __restrict__ out) {
    int tid = threadIdx.x;
    float s = psum[tid] + psum[tid + 256];
    unsigned int c = pcnt[tid] + pcnt[tid + 256];
    for (int off = 32; off; off >>= 1) {
        s += __shfl_down(s, off);
        c += __shfl_down(c, off);
    }
    __shared__ float ws[4];
    __shared__ unsigned int wc[4];
    int lane = tid & 63, wid = tid >> 6;
    if (lane == 0) { ws[wid] = s; wc[wid] = c; }
    __syncthreads();
    if (tid == 0) {
        float tot = ws[0] + ws[1] + ws[2] + ws[3];
        unsigned int cnt = wc[0] + wc[1] + wc[2] + wc[3];
        out[0] = tot / (float)(cnt ? cnt : 1u);
    }
}

extern "C" void kernel_launch(void* const* d_in, const int* in_sizes, int n_in,
                              void* d_out, int out_size, void* d_ws, size_t ws_size,
                              hipStream_t stream) {
    const float* x = (const float*)d_in[0];
    const int* t = (const int*)d_in[1];
    float* out = (float*)d_out;

    char* ws = (char*)d_ws;
    const size_t OFF_PART = 0;                                  // 8 MiB (8 planes)
    const size_t OFF_DIAG = (size_t)KZ * NPTS * NPTS * 4;       // 16 KiB
    const size_t OFF_PSUM = OFF_DIAG + (size_t)KZ * NPTS * 4;   // 2 KiB
    const size_t OFF_PCNT = OFF_PSUM + 2048;                    // 2 KiB

    float* part        = (float*)(ws + OFF_PART);
    float* diag        = (float*)(ws + OFF_DIAG);
    float* psum        = (float*)(ws + OFF_PSUM);
    unsigned int* pcnt = (unsigned int*)(ws + OFF_PCNT);

    gram_kernel<<<dim3(8, 8, KZ), 256, 0, stream>>>(x, part, diag);
    triplet_kernel<<<NPTS, 256, 0, stream>>>(part, diag, t, psum, pcnt);
    finalize_kernel<<<1, 256, 0, stream>>>(psum, pcnt, out);
}

// Round 3
// 25.336 us; speedup vs baseline: 1.2375x; 1.0058x over previous
//
#include <hip/hip_runtime.h>
#include <math.h>

#define NPTS 512
#define DIM  2048
#define MARGIN_F 0.5f
#define KZ 8
#define KCHUNK (DIM / KZ)   // 256

typedef __attribute__((ext_vector_type(4))) float f32x4;
typedef __attribute__((ext_vector_type(8))) short bf16x8;
typedef __attribute__((ext_vector_type(4))) unsigned int u32x4;

// f32 pair -> packed bf16 (RNE). Lowers to v_cvt_pk_bf16_f32 on gfx950.
__device__ inline unsigned int pkbf(float lo, float hi) {
    unsigned short ul = __builtin_bit_cast(unsigned short, (__bf16)lo);
    unsigned short uh = __builtin_bit_cast(unsigned short, (__bf16)hi);
    return (unsigned int)ul | ((unsigned int)uh << 16);
}

// ---------- kernel 1: split-K Gram partials, f32->bf16 fused into staging.
// grid (8, 8, 8) = 512 blocks (2/CU); 256 thr = 4 waves as 2x2, each wave a
// 32x32 quadrant = 2x2 frags of 16x16x32. K-loop is software-pipelined 2-deep
// (T14): iteration k+1's global loads are issued before iteration k's
// convert+LDS+MFMA, hiding the ~400-900cy load latency that R2 showed was the
// bottleneck (conversion-VALU cut was neutral -> latency-bound).
__global__ __launch_bounds__(256) void gram_kernel(const float* __restrict__ x,
                                                   float* __restrict__ part,
                                                   float* __restrict__ diag) {
    __shared__ __align__(16) unsigned short As[64][72];  // +8 pad
    __shared__ __align__(16) unsigned short Bs[64][72];

    int bx = blockIdx.x, by = blockIdx.y, z = blockIdx.z;
    int tid = threadIdx.x;
    int lr = tid >> 2;            // staging row 0..63
    int lc = (tid & 3) * 16;      // staging col (elements) 0,16,32,48

    const float* arow = x + (size_t)(bx * 64 + lr) * DIM + (size_t)z * KCHUNK + lc;
    const float* brow = x + (size_t)(by * 64 + lr) * DIM + (size_t)z * KCHUNK + lc;

    int w = tid >> 6, lane = tid & 63;
    int wr = (w >> 1) * 32, wc = (w & 1) * 32;
    int fr = lane & 15, ko = (lane >> 4) * 8;

    f32x4 acc[2][2] = {};

    // 2-deep register pipeline. Arrays are statically indexed via full unroll
    // (rule #20: runtime-indexed ext_vector arrays spill to scratch).
    float4 ca[4], cb[4], na[4], nb[4];
#pragma unroll
    for (int q = 0; q < 4; ++q) {
        ca[q] = *reinterpret_cast<const float4*>(arow + 4 * q);
        cb[q] = *reinterpret_cast<const float4*>(brow + 4 * q);
    }

#pragma unroll
    for (int it = 0; it < 4; ++it) {
        if (it < 3) {
            int ks = (it + 1) * 64;
#pragma unroll
            for (int q = 0; q < 4; ++q) {
                na[q] = *reinterpret_cast<const float4*>(arow + ks + 4 * q);
                nb[q] = *reinterpret_cast<const float4*>(brow + ks + 4 * q);
            }
        }
        u32x4 wa0 = { pkbf(ca[0].x, ca[0].y), pkbf(ca[0].z, ca[0].w),
                      pkbf(ca[1].x, ca[1].y), pkbf(ca[1].z, ca[1].w) };
        u32x4 wa1 = { pkbf(ca[2].x, ca[2].y), pkbf(ca[2].z, ca[2].w),
                      pkbf(ca[3].x, ca[3].y), pkbf(ca[3].z, ca[3].w) };
        u32x4 wb0 = { pkbf(cb[0].x, cb[0].y), pkbf(cb[0].z, cb[0].w),
                      pkbf(cb[1].x, cb[1].y), pkbf(cb[1].z, cb[1].w) };
        u32x4 wb1 = { pkbf(cb[2].x, cb[2].y), pkbf(cb[2].z, cb[2].w),
                      pkbf(cb[3].x, cb[3].y), pkbf(cb[3].z, cb[3].w) };
        // byte offsets: lr*144 + lc*2 with lc in {0,16,32,48} -> 16B-aligned
        *reinterpret_cast<u32x4*>(&As[lr][lc])     = wa0;
        *reinterpret_cast<u32x4*>(&As[lr][lc + 8]) = wa1;
        *reinterpret_cast<u32x4*>(&Bs[lr][lc])     = wb0;
        *reinterpret_cast<u32x4*>(&Bs[lr][lc + 8]) = wb1;
        __syncthreads();
#pragma unroll
        for (int kc = 0; kc < 2; ++kc) {
            bf16x8 fa0 = *reinterpret_cast<const bf16x8*>(&As[wr + fr][kc * 32 + ko]);
            bf16x8 fa1 = *reinterpret_cast<const bf16x8*>(&As[wr + 16 + fr][kc * 32 + ko]);
            bf16x8 fb0 = *reinterpret_cast<const bf16x8*>(&Bs[wc + fr][kc * 32 + ko]);
            bf16x8 fb1 = *reinterpret_cast<const bf16x8*>(&Bs[wc + 16 + fr][kc * 32 + ko]);
            acc[0][0] = __builtin_amdgcn_mfma_f32_16x16x32_bf16(fa0, fb0, acc[0][0], 0, 0, 0);
            acc[0][1] = __builtin_amdgcn_mfma_f32_16x16x32_bf16(fa0, fb1, acc[0][1], 0, 0, 0);
            acc[1][0] = __builtin_amdgcn_mfma_f32_16x16x32_bf16(fa1, fb0, acc[1][0], 0, 0, 0);
            acc[1][1] = __builtin_amdgcn_mfma_f32_16x16x32_bf16(fa1, fb1, acc[1][1], 0, 0, 0);
        }
        __syncthreads();
        if (it < 3) {
#pragma unroll
            for (int q = 0; q < 4; ++q) { ca[q] = na[q]; cb[q] = nb[q]; }
        }
    }

    float* pg = part + (size_t)z * NPTS * NPTS;
    int rbase = bx * 64 + wr + ((lane >> 4) << 2);  // C/D: row = (lane>>4)*4 + reg
    int cbase = by * 64 + wc + fr;                  //      col = lane&15
#pragma unroll
    for (int m = 0; m < 2; ++m)
#pragma unroll
        for (int n = 0; n < 2; ++n) {
            f32x4 v = acc[m][n];
#pragma unroll
            for (int j = 0; j < 4; ++j)
                pg[(size_t)(rbase + m * 16 + j) * NPTS + (cbase + n * 16)] = v[j];
        }

    // compact diagonal: tile diag lives in waves with wr==wc, frags m==n,
    // lanes where fr>>2 == lane>>4 (then row==col at j = fr&3).
    if (bx == by && wr == wc && (fr >> 2) == (lane >> 4)) {
        int j = fr & 3;
#pragma unroll
        for (int m = 0; m < 2; ++m)
            diag[(size_t)z * NPTS + bx * 64 + wr + m * 16 + fr] = acc[m][m][j];
    }
}

// ---------- kernel 2: per-anchor hinge; norms from compact diag ----------
// part-row gather issued at kernel entry (T14 issue-early): its latency hides
// under the targets-sniff and diag->sqv phases. float2 x 256 threads engages
// the whole block (old float4/128-thread loop idled half of it).
__global__ __launch_bounds__(256) void triplet_kernel(const float* __restrict__ part,
                                                      const float* __restrict__ diag,
                                                      const int* __restrict__ traw,
                                                      float* __restrict__ psum,
                                                      unsigned int* __restrict__ pcnt) {
    __shared__ float drow[NPTS];
    __shared__ float sqv[NPTS];
    __shared__ int   tl[NPTS];
    __shared__ int   pos[NPTS];
    __shared__ int   is64;
    __shared__ unsigned long long wmask[8];
    __shared__ float wsum[4];
    __shared__ unsigned int wcnt[4];

    int a = blockIdx.x, tid = threadIdx.x;
    int lane = tid & 63, wid = tid >> 6;

    // issue the dist-row gather immediately (needs only a, tid)
    const size_t PL = (size_t)NPTS * NPTS;
    float2 g[KZ];
#pragma unroll
    for (int z = 0; z < KZ; ++z)
        g[z] = reinterpret_cast<const float2*>(part + (size_t)z * PL + (size_t)a * NPTS)[tid];

    if (tid == 0) is64 = 1;
    __syncthreads();

    // int64 vs int32 targets sniff (ids < 64 -> odd words all zero iff i64)
    for (int i = tid; i < NPTS / 2; i += 256)
        if (traw[2 * i + 1] != 0) is64 = 0;
    __syncthreads();
    if (is64) { for (int i = tid; i < NPTS; i += 256) tl[i] = traw[2 * i]; }
    else      { for (int i = tid; i < NPTS; i += 256) tl[i] = traw[i]; }

    // squared norms from compact per-plane diag (contiguous reads)
    for (int j = tid; j < NPTS; j += 256) {
        float s = 0.f;
#pragma unroll
        for (int z = 0; z < KZ; ++z) s += diag[(size_t)z * NPTS + j];
        sqv[j] = s;
    }
    __syncthreads();

    // consume gather: dist row a (z-sum order identical to before)
    float sqa = sqv[a];
    {
        float gx = 0.f, gy = 0.f;
#pragma unroll
        for (int z = 0; z < KZ; ++z) { gx += g[z].x; gy += g[z].y; }
        float d2;
        d2 = sqa + sqv[2 * tid + 0] - 2.f * gx; drow[2 * tid + 0] = d2 > 0.f ? sqrtf(d2) : 0.f;
        d2 = sqa + sqv[2 * tid + 1] - 2.f * gy; drow[2 * tid + 1] = d2 > 0.f ? sqrtf(d2) : 0.f;
    }
    __syncthreads();

    // deterministic positive-list compaction via ballot prefix
    int ta = tl[a];
    unsigned long long bal[2];
    bool m[2];
#pragma unroll
    for (int p = 0; p < 2; ++p) {
        int j = p * 256 + tid;
        m[p] = (tl[j] == ta) && (j != a);
        bal[p] = __ballot(m[p]);
        if (lane == 0) wmask[p * 4 + wid] = bal[p];
    }
    __syncthreads();
    int np = 0;
#pragma unroll
    for (int k = 0; k < 8; ++k) np += __popcll(wmask[k]);
#pragma unroll
    for (int p = 0; p < 2; ++p) {
        if (m[p]) {
            int widx = p * 4 + wid, base = 0;
            for (int k = 0; k < widx; ++k) base += __popcll(wmask[k]);
            base += __popcll(bal[p] & ((1ull << lane) - 1ull));
            pos[base] = p * 256 + tid;
        }
    }
    __syncthreads();

    float sum = 0.f;
    unsigned int cnt = 0;
    int tot = np << 9;
    for (int idx = tid; idx < tot; idx += 256) {
        int p = pos[idx >> 9];
        int n = idx & (NPTS - 1);
        if (tl[n] != ta) {
            float v = drow[p] - drow[n] + MARGIN_F;
            if (v > 0.f) { sum += v; cnt++; }
        }
    }

    for (int off = 32; off; off >>= 1) {
        sum += __shfl_down(sum, off);
        cnt += __shfl_down(cnt, off);
    }
    if (lane == 0) { wsum[wid] = sum; wcnt[wid] = cnt; }
    __syncthreads();
    if (tid == 0) {
        psum[a] = wsum[0] + wsum[1] + wsum[2] + wsum[3];
        pcnt[a] = wcnt[0] + wcnt[1] + wcnt[2] + wcnt[3];
    }
}

// ---------- kernel 3: final reduction over 512 per-anchor partials ----------
__global__ __launch_bounds__(256) void finalize_kernel(const float* __restrict__ psum,
                                                       const unsigned int* __restrict__ pcnt,
                                                       float* __restrict__ out) {
    int tid = threadIdx.x;
    float s = psum[tid] + psum[tid + 256];
    unsigned int c = pcnt[tid] + pcnt[tid + 256];
    for (int off = 32; off; off >>= 1) {
        s += __shfl_down(s, off);
        c += __shfl_down(c, off);
    }
    __shared__ float ws[4];
    __shared__ unsigned int wc[4];
    int lane = tid & 63, wid = tid >> 6;
    if (lane == 0) { ws[wid] = s; wc[wid] = c; }
    __syncthreads();
    if (tid == 0) {
        float tot = ws[0] + ws[1] + ws[2] + ws[3];
        unsigned int cnt = wc[0] + wc[1] + wc[2] + wc[3];
        out[0] = tot / (float)(cnt ? cnt : 1u);
    }
}

extern "C" void kernel_launch(void* const* d_in, const int* in_sizes, int n_in,
                              void* d_out, int out_size, void* d_ws, size_t ws_size,
                              hipStream_t stream) {
    const float* x = (const float*)d_in[0];
    const int* t = (const int*)d_in[1];
    float* out = (float*)d_out;

    char* ws = (char*)d_ws;
    const size_t OFF_PART = 0;                                  // 8 MiB (8 planes)
    const size_t OFF_DIAG = (size_t)KZ * NPTS * NPTS * 4;       // 16 KiB
    const size_t OFF_PSUM = OFF_DIAG + (size_t)KZ * NPTS * 4;   // 2 KiB
    const size_t OFF_PCNT = OFF_PSUM + 2048;                    // 2 KiB

    float* part        = (float*)(ws + OFF_PART);
    float* diag        = (float*)(ws + OFF_DIAG);
    float* psum        = (float*)(ws + OFF_PSUM);
    unsigned int* pcnt = (unsigned int*)(ws + OFF_PCNT);

    gram_kernel<<<dim3(8, 8, KZ), 256, 0, stream>>>(x, part, diag);
    triplet_kernel<<<NPTS, 256, 0, stream>>>(part, diag, t, psum, pcnt);
    finalize_kernel<<<1, 256, 0, stream>>>(psum, pcnt, out);
}